// Round 7
// baseline (253.692 us; speedup 1.0000x reference)
//
#include <hip/hip_runtime.h>
#include <hip/hip_bf16.h>
#include <math.h>

#define NEGV -1e30f
#define LN2F 0.6931471805599453f

// B=16, T=800, D=512, V=4000 (padded to 4096), Lmax=100, S=201
// M = B*T = 12800 rows.

typedef __attribute__((ext_vector_type(8))) short bf16x8;
typedef __attribute__((ext_vector_type(4))) float f32x4;

__device__ __forceinline__ short f2bf(float x) {
    __hip_bfloat16 h = __float2bfloat16(x);
    return __builtin_bit_cast(short, h);
}
__device__ __forceinline__ float bflo(unsigned int u) { return __int_as_float(u << 16); }
__device__ __forceinline__ float bfhi(unsigned int u) { return __int_as_float(u & 0xffff0000u); }

// wave-wide shift-up-by-1 with zero fill, on the VALU (DPP wave_shr:1),
// ~4 cyc vs ~50+ for ds_bpermute-based __shfl_up.
__device__ __forceinline__ float shup1(float x) {
    return __builtin_bit_cast(float,
        __builtin_amdgcn_update_dpp(0, __builtin_bit_cast(int, x),
                                    0x138, 0xf, 0xf, true));
}

#define GLD_LDS(g, l) \
    __builtin_amdgcn_global_load_lds( \
        (const __attribute__((address_space(1))) void*)(g), \
        (__attribute__((address_space(3))) void*)(l), 16, 0, 0)

// ---------------------------------------------------------------------------
// prep: fused conv_wt (blocks 0..1023) + conv_ah (1024..4223) + setup (4224).
// ---------------------------------------------------------------------------
__global__ __launch_bounds__(256) void prep(
    const float* __restrict__ hs, const float* __restrict__ W,
    const float* __restrict__ bias, const int* __restrict__ ys,
    short* __restrict__ Wt, short* __restrict__ Ah,
    float* __restrict__ biasp, unsigned char* __restrict__ M,
    unsigned char* __restrict__ canon, float* __restrict__ lse_sum,
    float* __restrict__ out)
{
    __shared__ float tile[32][65];
    __shared__ unsigned char mapl[4096];
    const int bx = blockIdx.x, tid = threadIdx.x;

    if (bx < 1024) {
        const int n0 = (bx & 63) * 64;
        const int k0 = (bx >> 6) * 32;
        #pragma unroll
        for (int p = 0; p < 8; p++) {
            int idx = p * 256 + tid;
            int k = idx >> 6, n = idx & 63;
            int gn = n0 + n;
            tile[k][n] = (gn < 4000) ? W[(size_t)(k0 + k) * 4000 + gn] : 0.0f;
        }
        __syncthreads();
        #pragma unroll
        for (int p = 0; p < 8; p++) {
            int idx = p * 256 + tid;
            int n = idx >> 5, k = idx & 31;
            Wt[(size_t)(n0 + n) * 512 + k0 + k] = f2bf(tile[k][n]);
        }
    } else if (bx < 4224) {
        size_t i = ((size_t)(bx - 1024) * 256 + tid) * 8;
        float4 u = *(const float4*)(hs + i);
        float4 v = *(const float4*)(hs + i + 4);
        bf16x8 r;
        r[0] = f2bf(u.x); r[1] = f2bf(u.y); r[2] = f2bf(u.z); r[3] = f2bf(u.w);
        r[4] = f2bf(v.x); r[5] = f2bf(v.y); r[6] = f2bf(v.z); r[7] = f2bf(v.w);
        *(bf16x8*)(Ah + i) = r;
    } else {
        for (int b = 0; b < 16; b++) {
            for (int i = tid; i < 1024; i += 256)
                ((unsigned int*)mapl)[i] = 0xFFFFFFFFu;
            __syncthreads();
            if (tid == 0) mapl[0] = 0;
            __syncthreads();
            if (tid < 100) mapl[ys[b * 100 + tid]] = (unsigned char)(tid + 1);
            __syncthreads();
            for (int i = tid; i < 1024; i += 256)
                ((unsigned int*)(M + (size_t)b * 4096))[i] = ((const unsigned int*)mapl)[i];
            if (tid < 128) {
                int colc = (tid >= 1 && tid <= 100) ? ys[b * 100 + tid - 1] : 0;
                canon[b * 128 + tid] = mapl[colc];
            }
            __syncthreads();
        }
        for (int i = tid; i < 4096; i += 256)
            biasp[i] = (i < 4000) ? bias[i] : NEGV;
        for (int i = tid; i < 12800; i += 256)
            lse_sum[i] = 0.0f;
        if (tid == 0) out[0] = 0.0f;
    }
}

// ---------------------------------------------------------------------------
// Streaming-sumexp GEMM, double-buffered global_load_lds staging.
// grid (100, 32) x 256. Prefetch for k+1 issues before compute of k; one
// barrier per K-iter. LDS k-chunk XOR-swizzle -> conflict-free reads.
// ---------------------------------------------------------------------------
__global__ __launch_bounds__(256) void lse_mfma(
    const short* __restrict__ Ah,     // [12800][512] bf16
    const short* __restrict__ Wt,     // [4096][512] bf16
    const float* __restrict__ biasp,  // [4096]
    const unsigned char* __restrict__ M,  // [16][4096]
    float* __restrict__ lse_sum,      // [12800]
    __hip_bfloat16* __restrict__ Praw)// [12800][128]
{
    __shared__ short As[2][128 * 32];
    __shared__ short Bs[2][128 * 32];

    const int tid = threadIdx.x;
    const int w = tid >> 6, lane = tid & 63;
    const int quad = lane >> 4, l16 = lane & 15;
    const int wm = w >> 1, wn = w & 1;
    const int row0 = blockIdx.x * 128;
    const int col0 = blockIdx.y * 128;

    const int c0 = tid, c1 = tid + 256;
    const int g0 = (c0 & 3) ^ ((c0 >> 3) & 3);
    const int g1 = (c1 & 3) ^ ((c1 >> 3) & 3);
    const short* agp0 = Ah + (size_t)(row0 + (c0 >> 2)) * 512 + g0 * 8;
    const short* agp1 = Ah + (size_t)(row0 + (c1 >> 2)) * 512 + g1 * 8;
    const short* bgp0 = Wt + (size_t)(col0 + (c0 >> 2)) * 512 + g0 * 8;
    const short* bgp1 = Wt + (size_t)(col0 + (c1 >> 2)) * 512 + g1 * 8;

    f32x4 acc[4][4];
    #pragma unroll
    for (int mi = 0; mi < 4; mi++)
        #pragma unroll
        for (int ni = 0; ni < 4; ni++) acc[mi][ni] = (f32x4){0.f,0.f,0.f,0.f};

    const int sw = (l16 >> 1) & 3;

    // prologue: stage k-iter 0 into buffer 0
    GLD_LDS(agp0, As[0] + c0 * 8);
    GLD_LDS(agp1, As[0] + c1 * 8);
    GLD_LDS(bgp0, Bs[0] + c0 * 8);
    GLD_LDS(bgp1, Bs[0] + c1 * 8);
    __syncthreads();

    for (int it = 0; it < 16; it++) {
        const int cur = it & 1, nxt = cur ^ 1;
        if (it < 15) {
            const int kn = (it + 1) * 32;
            GLD_LDS(agp0 + kn, As[nxt] + c0 * 8);
            GLD_LDS(agp1 + kn, As[nxt] + c1 * 8);
            GLD_LDS(bgp0 + kn, Bs[nxt] + c0 * 8);
            GLD_LDS(bgp1 + kn, Bs[nxt] + c1 * 8);
        }
        bf16x8 af[4], bfr[4];
        #pragma unroll
        for (int mi = 0; mi < 4; mi++)
            af[mi] = *(const bf16x8*)&As[cur][(wm * 64 + mi * 16 + l16) * 32 + ((quad ^ sw) * 8)];
        #pragma unroll
        for (int ni = 0; ni < 4; ni++)
            bfr[ni] = *(const bf16x8*)&Bs[cur][(wn * 64 + ni * 16 + l16) * 32 + ((quad ^ sw) * 8)];
        #pragma unroll
        for (int mi = 0; mi < 4; mi++)
            #pragma unroll
            for (int ni = 0; ni < 4; ni++)
                acc[mi][ni] = __builtin_amdgcn_mfma_f32_16x16x32_bf16(
                    af[mi], bfr[ni], acc[mi][ni], 0, 0, 0);
        __syncthreads();
    }

    // epilogue: sumexp partials + scatter label-column logits
    const int b0 = row0 / 800;
    const int b1 = (b0 + 1 < 16) ? b0 + 1 : 15;
    const int bbound = (b0 + 1) * 800;
    float s[16];
    #pragma unroll
    for (int i = 0; i < 16; i++) s[i] = 0.0f;
    #pragma unroll
    for (int ni = 0; ni < 4; ni++) {
        int col = col0 + wn * 64 + ni * 16 + l16;
        float bj = biasp[col];
        unsigned char sl0 = M[(size_t)b0 * 4096 + col];
        unsigned char sl1 = M[(size_t)b1 * 4096 + col];
        #pragma unroll
        for (int mi = 0; mi < 4; mi++) {
            #pragma unroll
            for (int r = 0; r < 4; r++) {
                int row = row0 + wm * 64 + mi * 16 + quad * 4 + r;
                float v = acc[mi][ni][r] + bj;
                s[mi * 4 + r] += __expf(v);
                unsigned char sl = (row < bbound) ? sl0 : sl1;
                if (sl != 255)
                    Praw[(size_t)row * 128 + sl] = __float2bfloat16(v);
            }
        }
    }
    #pragma unroll
    for (int off = 1; off < 16; off <<= 1)
        #pragma unroll
        for (int i = 0; i < 16; i++) s[i] += __shfl_xor(s[i], off);
    if (l16 == 0) {
        #pragma unroll
        for (int mi = 0; mi < 4; mi++)
            #pragma unroll
            for (int r = 0; r < 4; r++)
                atomicAdd(&lse_sum[row0 + wm * 64 + mi * 16 + quad * 4 + r],
                          s[mi * 4 + r]);
    }
}

// ---------------------------------------------------------------------------
// CTC forward DP, probability domain, two steps fused per iteration.
// DPP wave_shr for neighbor states (VALU-latency, no LDS on the chain).
// ---------------------------------------------------------------------------
__global__ __launch_bounds__(256) void ctc_dp(
    const __hip_bfloat16* __restrict__ Praw,  // [12800][128]
    const float* __restrict__ lse_sum,        // [12800]
    const unsigned char* __restrict__ canon,  // [16][128]
    const int* __restrict__ hlens,
    const int* __restrict__ ys,
    const int* __restrict__ ylens,
    float* __restrict__ out)
{
    const int b = blockIdx.x, tid = threadIdx.x;
    const int w = tid >> 6, lane = tid & 63;
    __shared__ float bufF[2][64 * 128];   // 64 KB
    __shared__ float sA[256];

    const __hip_bfloat16* Pb = Praw + (size_t)b * 800 * 128;
    const float* lsb = lse_sum + b * 800;
    const int hl = hlens[b], L = ylens[b];
    const int t_stop = hl - 1;
    const int C = (t_stop + 63) >> 6;

    const int yb = b * 100;
    const unsigned char* cb = canon + b * 128;
    float kA = 0.f, kB = 0.f, kH = 0.f;
    if (lane >= 1 && 2 * lane <= 99)
        kA = (ys[yb + 2 * lane] != ys[yb + 2 * lane - 1]) ? 1.f : 0.f;
    if (2 * lane + 1 <= 99)
        kB = (ys[yb + 2 * lane + 1] != ys[yb + 2 * lane]) ? 1.f : 0.f;
    if (lane >= 1 && 2 * lane - 1 <= 99)
        kH = (ys[yb + 2 * lane - 1] != ys[yb + 2 * lane - 2]) ? 1.f : 0.f;
    const int slotA = cb[(2 * lane + 1 < 128) ? 2 * lane + 1 : 127];
    const int slotB = cb[(2 * lane + 2 < 128) ? 2 * lane + 2 : 127];
    const int slotH = cb[(2 * lane < 128) ? 2 * lane : 127];
    const float m0  = (lane <= 50) ? 1.f : 0.f;
    const float m13 = (lane <= 49) ? 1.f : 0.f;

    float a0 = 0.f, a1 = 0.f, a2 = 0.f, a3 = 0.f;
    if (w == 0 && lane == 0) {
        float sc0 = __builtin_amdgcn_rcpf(lsb[0]) * 2048.0f;
        a0 = __expf(__bfloat162float(Pb[0])) * sc0;
        a1 = __expf(__bfloat162float(Pb[cb[1]])) * sc0;
    }
    int kacc = 0;

    // stage chunk 0: rows t = 1..64
    for (int idx = tid; idx < 1024; idx += 256) {
        int i = idx >> 4, cs = (idx & 15) << 3;
        int tr = 1 + i; if (tr > 799) tr = 799;
        float sc = __builtin_amdgcn_rcpf(lsb[tr]) * 2048.0f;
        uint4 v = *(const uint4*)(Pb + (size_t)tr * 128 + cs);
        float* d = &bufF[0][i * 128 + cs];
        float4 o0, o1;
        o0.x = __expf(bflo(v.x)) * sc; o0.y = __expf(bfhi(v.x)) * sc;
        o0.z = __expf(bflo(v.y)) * sc; o0.w = __expf(bfhi(v.y)) * sc;
        o1.x = __expf(bflo(v.z)) * sc; o1.y = __expf(bfhi(v.z)) * sc;
        o1.z = __expf(bflo(v.w)) * sc; o1.w = __expf(bfhi(v.w)) * sc;
        *(float4*)d = o0;
        *(float4*)(d + 4) = o1;
    }
    __syncthreads();

    for (int ch = 0; ch < C; ch++) {
        if (w > 0) {
            int nc = ch + 1;
            if (nc < C) {
                float* dst = bufF[nc & 1];
                const int tbase = 64 * nc + 1;
                for (int idx = tid - 64; idx < 1024; idx += 192) {
                    int i = idx >> 4, cs = (idx & 15) << 3;
                    int tr = tbase + i; if (tr > 799) tr = 799;
                    float sc = __builtin_amdgcn_rcpf(lsb[tr]) * 2048.0f;
                    uint4 v = *(const uint4*)(Pb + (size_t)tr * 128 + cs);
                    float* d = &dst[i * 128 + cs];
                    float4 o0, o1;
                    o0.x = __expf(bflo(v.x)) * sc; o0.y = __expf(bfhi(v.x)) * sc;
                    o0.z = __expf(bflo(v.y)) * sc; o0.w = __expf(bfhi(v.y)) * sc;
                    o1.x = __expf(bflo(v.z)) * sc; o1.y = __expf(bfhi(v.z)) * sc;
                    o1.z = __expf(bflo(v.w)) * sc; o1.w = __expf(bfhi(v.w)) * sc;
                    *(float4*)d = o0;
                    *(float4*)(d + 4) = o1;
                }
            }
        } else {
            const float* bb = bufF[ch & 1];
            const int t0 = 64 * ch + 1;
            if (t0 + 63 <= t_stop) {
                // ---- fast path: 32 fused pairs ----
                float pbt  = bb[0];
                float pbn  = bb[128];
                float pht  = bb[slotH];
                float pat  = bb[slotA];
                float pan  = bb[128 + slotA];
                float pqt  = bb[slotB];
                float pqn  = bb[128 + slotB];
                #pragma unroll
                for (int k = 0; k < 32; k++) {
                    float n_pbt = 0.f, n_pbn = 0.f, n_pht = 0.f,
                          n_pat = 0.f, n_pan = 0.f, n_pqt = 0.f, n_pqn = 0.f;
                    if (k < 31) {
                        const float* r0 = bb + (2 * k + 2) * 128;
                        const float* r1 = bb + (2 * k + 3) * 128;
                        n_pbt = r0[0];     n_pbn = r1[0];
                        n_pht = r0[slotH];
                        n_pat = r0[slotA]; n_pan = r1[slotA];
                        n_pqt = r0[slotB]; n_pqn = r1[slotB];
                    }
                    float h1 = shup1(a3);
                    float h2 = shup1(a2);
                    float h3 = shup1(a1);
                    float tm1 = fmaf(kH, h3, h1 + h2);
                    float t0v = a0 + h1;
                    float t1v = fmaf(kA, h1, a1 + a0);
                    float t2v = a2 + a1;
                    float t3v = fmaf(kB, a1, a3 + a2);
                    float um1 = pht * tm1;
                    float u0 = pbt * t0v, u1 = pat * t1v;
                    float u2 = pbt * t2v, u3 = pqt * t3v;
                    a0 = (pbn * (u0 + um1)) * m0;
                    a1 = (pan * fmaf(kA, um1, u1 + u0)) * m13;
                    a2 = (pbn * (u2 + u1)) * m13;
                    a3 = (pqn * fmaf(kB, u1, u3 + u2)) * m13;
                    if ((k & 7) == 7) {
                        int tc = t0 + 2 * k + 1;
                        float lm = fmaxf(fmaxf(a0, a1), fmaxf(a2, a3));
                        int sa1 = (2 * L < tc) ? 2 * L : tc;
                        int sa2 = (int)(2.0f * L * tc / hl);
                        float v1 = __shfl(lm, sa1 >> 2);
                        float v2 = __shfl(lm, sa2 >> 2);
                        float av = fmaxf(v1, v2);
                        int eb = (__float_as_int(av) >> 23) & 0xFF;
                        if (eb != 0 && eb != 255) {
                            int e = eb - 127;
                            kacc += e;
                            float sc = __int_as_float((127 - e) << 23);
                            a0 *= sc; a1 *= sc; a2 *= sc; a3 *= sc;
                        }
                    }
                    pbt = n_pbt; pbn = n_pbn; pht = n_pht;
                    pat = n_pat; pan = n_pan; pqt = n_pqt; pqn = n_pqn;
                }
            } else {
                // ---- slow tail: single steps ----
                for (int t = t0; t <= t_stop; t++) {
                    if ((t & 15) == 0) {
                        float lm = fmaxf(fmaxf(a0, a1), fmaxf(a2, a3));
                        int sa1 = (2 * L < t) ? 2 * L : t;
                        int sa2 = (int)(2.0f * L * t / hl);
                        float v1 = __shfl(lm, sa1 >> 2);
                        float v2 = __shfl(lm, sa2 >> 2);
                        float av = fmaxf(v1, v2);
                        int eb = (__float_as_int(av) >> 23) & 0xFF;
                        if (eb != 0 && eb != 255) {
                            int e = eb - 127;
                            kacc += e;
                            float sc = __int_as_float((127 - e) << 23);
                            a0 *= sc; a1 *= sc; a2 *= sc; a3 *= sc;
                        }
                    }
                    const float* r = bb + (t - t0) * 128;
                    float e0 = r[0], eA = r[slotA], eB = r[slotB];
                    float p3 = shup1(a3);
                    float n0 = (a0 + p3) * e0;
                    float n1 = fmaf(kA, p3, a1 + a0) * eA;
                    float n2 = (a2 + a1) * e0;
                    float n3 = fmaf(kB, a1, a3 + a2) * eB;
                    a0 = n0 * m0; a1 = n1 * m13; a2 = n2 * m13; a3 = n3 * m13;
                }
            }
        }
        __syncthreads();
    }

    if (w == 0) {
        sA[lane * 4 + 0] = a0; sA[lane * 4 + 1] = a1;
        sA[lane * 4 + 2] = a2; sA[lane * 4 + 3] = a3;
    }
    __syncthreads();

    if (tid == 0) {
        int idx = 2 * L;
        float s = sA[idx] + sA[idx - 1];
        float la = __logf(s) + (float)(kacc - 11 * hl) * LN2F;
        float loss = -la;
        if (!isfinite(loss) || loss >= 1e29f) loss = 0.0f;
        atomicAdd(out, loss * 0.0625f);
    }
}

// ---------------------------------------------------------------------------
extern "C" void kernel_launch(void* const* d_in, const int* in_sizes, int n_in,
                              void* d_out, int out_size, void* d_ws, size_t ws_size,
                              hipStream_t stream)
{
    const float* hs    = (const float*)d_in[0];   // [16,800,512]
    const float* W     = (const float*)d_in[1];   // [512,4000]
    const float* bias  = (const float*)d_in[2];   // [4000]
    const int*   hlens = (const int*)d_in[3];     // [16]
    const int*   ys    = (const int*)d_in[4];     // [16,100]
    const int*   ylens = (const int*)d_in[5];     // [16]
    float* out = (float*)d_out;

    // workspace layout (bytes)
    char* wsb = (char*)d_ws;
    short* Wt      = (short*)(wsb);                         // 4,194,304
    short* Ah      = (short*)(wsb + 4194304);               // 13,107,200
    float* biasp   = (float*)(wsb + 17301504);              // 16,384
    __hip_bfloat16* Praw = (__hip_bfloat16*)(wsb + 17317888); // 3,276,800
    float* lse_sum = (float*)(wsb + 20594688);              // 51,200
    unsigned char* M     = (unsigned char*)(wsb + 20645888);// 65,536
    unsigned char* canon = (unsigned char*)(wsb + 20711424);// 2,048
    // total ~20.7 MB

    hipLaunchKernelGGL(prep,     dim3(4225),    dim3(256), 0, stream,
                       hs, W, bias, ys, Wt, Ah, biasp, M, canon, lse_sum, out);
    hipLaunchKernelGGL(lse_mfma, dim3(100, 32), dim3(256), 0, stream,
                       Ah, Wt, biasp, M, lse_sum, Praw);
    hipLaunchKernelGGL(ctc_dp,   dim3(16),      dim3(256), 0, stream,
                       Praw, lse_sum, canon, hlens, ys, ylens, out);
}